// Round 7
// baseline (1815.622 us; speedup 1.0000x reference)
//
#include <hip/hip_runtime.h>

#define D 100
#define TT 2048
#define BB 128
#define CHUNK 32
#define NCHUNK (TT / CHUNK)   /* 64 */
#define NTHR 896              /* 14 waves: 0=consumer, 1..12=producers, 13=stager */

static __device__ __constant__ float KLO = 2.8853900817779268f;   // 2*log2(e)
static __device__ __constant__ float MKF = -2.8853900817779268f;  // -2*log2(e)

// q += dpp_shuffle(q); ctrl must be an immediate
#define DPP_ADD(q, ctrl)                                                      \
  q += __int_as_float(__builtin_amdgcn_update_dpp(                            \
      0, __float_as_int(q), ctrl, 0xF, 0xF, true))

// ---------------------------------------------------------------------------
// K1: ab2m[j] = -log2(e) * (pos_table[j] . w_ap + b0)
// ---------------------------------------------------------------------------
__global__ void k1_pos(const float* __restrict__ pos, const float* __restrict__ wap,
                       const float* __restrict__ bb, float* __restrict__ ab2m) {
  int j = blockIdx.x * blockDim.x + threadIdx.x;
  if (j < TT) {
    float a = 0.f;
    #pragma unroll 4
    for (int e = 0; e < D; ++e) a = fmaf(pos[j * D + e], wap[e], a);
    ab2m[j] = -1.4426950408889634f * (a + bb[0]);
  }
}

// ---------------------------------------------------------------------------
// Fused scan, one block (14 waves) per batch row.
//   wave 0      : sequential chain (all steady-state reads from LDS)
//   waves 1..12 : g partial dots; wr half-rows REGISTER-resident, h via
//                 broadcast ds_read_b128 from hstage
//   wave 13     : stages h chunk cc+2 into hstage[(cc+2)%3]
// R6 NaN root cause: hstage pad columns [100..104) were read (13-float4 dot
// for the hf==1 half and for pad rows) but never written -> NaN via
// fmaf(NaN, 0, acc). Fix: stager writes zeros to the pad columns.
// ---------------------------------------------------------------------------
__global__ void __launch_bounds__(NTHR)
sp_scan(const float* __restrict__ h, const float* __restrict__ dv,
        const float* __restrict__ w_c, const float* __restrict__ w_s,
        const float* __restrict__ w_r, const float* __restrict__ ab2m,
        float* __restrict__ out) {
  __shared__ __align__(16) float gbuf[2][CHUNK][256];    // 64 KiB
  __shared__ __align__(16) float hstage[3][CHUNK][104];  // 39 KiB
  __shared__ float crow_s[128];
  const int b = blockIdx.x;
  const int tid = (int)threadIdx.x;
  const int lane = tid & 63;
  const int wvu = __builtin_amdgcn_readfirstlane(tid) >> 6;  // 0..13

  const float* hb = h + (size_t)b * TT * D;

  // ---- phase 1: crow partial sums (5 parts x 20 dd, 640 threads) ---------
  {
    float* sc = &gbuf[0][0][0];  // scratch overlay, dead before first produce
    if (tid < 640) {
      const int e = tid & 127;
      const int part = tid >> 7;  // 0..4
      float a1 = 0.f, a2 = 0.f;
      if (e < D) {
        const int d0 = part * 20;
        #pragma unroll 4
        for (int k = 0; k < 20; ++k) {
          const float dvv = dv[b * D + d0 + k];
          a1 = fmaf(dvv, w_s[(d0 + k) * D + e], a1);
          a2 += w_r[(d0 + k) * D + e];
        }
      }
      sc[part * 128 + e] = a1;
      sc[640 + part * 128 + e] = a2;
    }
  }
  __syncthreads();

  // producer task decode (wave-uniform)
  const int q = wvu - 1;
  const int grp = q >> 2;        // step group: s == grp (mod 3)
  const int blk = (q & 3) >> 1;  // row block
  const int hf = q & 1;          // element half
  const int eoff = hf ? 52 : 0;
  const int col = hf * 128 + blk * 64 + lane;
  const int row = blk * 64 + lane;

  float wr[52];

  // ---- phase 1b: crow reduce | producers load wr | stager stages chunk 0 --
  if (tid < 128) {
    const float* sc = &gbuf[0][0][0];
    float a1 = sc[tid] + sc[128 + tid] + sc[256 + tid] + sc[384 + tid] + sc[512 + tid];
    float a2 = sc[640 + tid] + sc[768 + tid] + sc[896 + tid] + sc[1024 + tid] + sc[1152 + tid];
    crow_s[tid] = (tid < D) ? (w_c[tid] + a1 - a2) : 0.f;
  }
  if (wvu >= 1 && wvu <= 12) {
    if (row < D) {
      const float4* src = (const float4*)(w_r + row * D + eoff);
      if (hf == 0) {
        #pragma unroll
        for (int k = 0; k < 13; ++k) {
          const float4 v = src[k];
          wr[4*k] = v.x; wr[4*k+1] = v.y; wr[4*k+2] = v.z; wr[4*k+3] = v.w;
        }
      } else {
        #pragma unroll
        for (int k = 0; k < 12; ++k) {
          const float4 v = src[k];
          wr[4*k] = v.x; wr[4*k+1] = v.y; wr[4*k+2] = v.z; wr[4*k+3] = v.w;
        }
        wr[48] = wr[49] = wr[50] = wr[51] = 0.f;
      }
    } else {
      #pragma unroll
      for (int k = 0; k < 52; ++k) wr[k] = 0.f;
    }
  } else if (wvu == 13) {
    for (int s = 0; s < CHUNK; ++s) {  // stage chunk 0 (+zero the pad cols)
      const float* hr = hb + (size_t)s * D;
      hstage[0][s][lane] = hr[lane];
      if (lane < 40) hstage[0][s][64 + lane] = (lane < 36) ? hr[64 + lane] : 0.f;
    }
  }
  __syncthreads();

  // consumer state
  float Slo = 0.f, Shi = 0.f, c = 0.f, hlp = 0.f, hhp = 0.f, pout = 0.f;
  float hlr0 = 0.f, hlr1 = 0.f, hhr0 = 0.f, hhr1 = 0.f, abrow_ = 0.f;

  // ---- phase 2: crow row | produce chunk 0 | stage chunk 1 | prime cons ---
  if (wvu == 0) {
    __builtin_amdgcn_s_setprio(1);
    abrow_ = ab2m[lane & 31];
    hlr0 = hstage[0][0][lane];
    hlr1 = hstage[0][1][lane];
    if (lane < 36) { hhr0 = hstage[0][0][64 + lane]; hhr1 = hstage[0][1][64 + lane]; }
  } else if (wvu <= 12) {
    if (row == D) {  // synthetic row 100 = crow
      const float* src = crow_s + eoff;
      if (hf == 0) {
        #pragma unroll
        for (int k = 0; k < 52; ++k) wr[k] = src[k];
      } else {
        #pragma unroll
        for (int k = 0; k < 48; ++k) wr[k] = src[k];
        wr[48] = wr[49] = wr[50] = wr[51] = 0.f;
      }
    }
    for (int s = grp; s < CHUNK; s += 3) {  // produce chunk 0
      const float4* hq = (const float4*)&hstage[0][s][eoff];
      float a0 = 0.f, a1 = 0.f;
      #pragma unroll
      for (int k = 0; k < 13; ++k) {
        const float4 v = hq[k];
        a0 = fmaf(v.x, wr[4*k+0], a0);
        a1 = fmaf(v.y, wr[4*k+1], a1);
        a0 = fmaf(v.z, wr[4*k+2], a0);
        a1 = fmaf(v.w, wr[4*k+3], a1);
      }
      gbuf[0][s][col] = a0 + a1;
    }
  } else {
    const float* hc = hb + (size_t)CHUNK * D;  // stage chunk 1
    for (int s = 0; s < CHUNK; ++s) {
      const float* hr = hc + (size_t)s * D;
      hstage[1][s][lane] = hr[lane];
      if (lane < 40) hstage[1][s][64 + lane] = (lane < 36) ? hr[64 + lane] : 0.f;
    }
  }
  __syncthreads();

  // ---- main loop: 64 windows ----------------------------------------------
  int bufc = 0;  // cc % 3
  for (int cc = 0; cc < NCHUNK; ++cc) {
    const int bufn = (bufc == 2) ? 0 : bufc + 1;
    if (wvu == 0) {
      float (*gb)[256] = gbuf[cc & 1];
      float g0l = gb[0][lane] + gb[0][128 + lane];
      float g0h = gb[0][64 + lane] + gb[0][192 + lane];
      float g1l = gb[1][lane] + gb[1][128 + lane];
      float g1h = gb[1][64 + lane] + gb[1][192 + lane];
      const int ncc = (cc + 1 < NCHUNK) ? cc + 1 : cc;
      float abn = ab2m[ncc * CHUNK + (lane & 31)];
      const bool notlast = (cc != NCHUNK - 1);
      #pragma unroll
      for (int s = 0; s < CHUNK; ++s) {
        float hlN = 0.f, hhN = 0.f;
        if (s < CHUNK - 2) {
          const float* hr = &hstage[bufc][s + 2][0];
          hlN = hr[lane];
          if (lane < 36) hhN = hr[64 + lane];
        } else if (notlast) {
          const float* hr = &hstage[bufn][s + 2 - CHUNK][0];
          hlN = hr[lane];
          if (lane < 36) hhN = hr[64 + lane];
        }
        float g2l = 0.f, g2h = 0.f;
        if (s < CHUNK - 2) {
          g2l = gb[s + 2][lane] + gb[s + 2][128 + lane];
          g2h = gb[s + 2][64 + lane] + gb[s + 2][192 + lane];
        }
        // ---- sequential chain ----
        Slo = fmaf(hlp, c, Slo);
        Shi = fmaf(hhp, c, Shi);
        float rlo = __builtin_amdgcn_rcpf(1.f + __builtin_amdgcn_exp2f(Slo));
        float rhi = __builtin_amdgcn_rcpf(1.f + __builtin_amdgcn_exp2f(Shi));
        float qq = rlo * g0l;
        qq = fmaf(rhi, g0h, qq);
        DPP_ADD(qq, 0xB1);
        DPP_ADD(qq, 0x4E);
        DPP_ADD(qq, 0x141);
        DPP_ADD(qq, 0x140);
        const int qi = __float_as_int(qq);
        float ra = __int_as_float(__builtin_amdgcn_readlane(qi, 0)) +
                   __int_as_float(__builtin_amdgcn_readlane(qi, 16));
        float rb = __int_as_float(__builtin_amdgcn_readlane(qi, 32)) +
                   __int_as_float(__builtin_amdgcn_readlane(qi, 48));
        float R = ra + rb;
        float abv = __int_as_float(
            __builtin_amdgcn_readlane(__float_as_int(abrow_), s));
        float nz = fmaf(MKF, R, abv);
        float p = __builtin_amdgcn_rcpf(1.f + __builtin_amdgcn_exp2f(nz));
        pout = (lane == s) ? p : pout;
        c = p;
        float hl_cur = (s & 1) ? hlr1 : hlr0;
        float hh_cur = (s & 1) ? hhr1 : hhr0;
        hlp = KLO * hl_cur;
        hhp = KLO * hh_cur;
        if (s == 0) {
          if (cc == 0) { hlp = 0.f; hhp = 0.f; }  // j==0 mask
        }
        if (s & 1) { hlr1 = hlN; hhr1 = hhN; } else { hlr0 = hlN; hhr0 = hhN; }
        g0l = g1l; g0h = g1h; g1l = g2l; g1h = g2h;
      }
      if (lane < CHUNK) out[(size_t)b * TT + cc * CHUNK + lane] = pout;
      abrow_ = abn;
    } else if (wvu <= 12) {
      if (cc + 1 < NCHUNK) {
        float (*gw)[256] = gbuf[(cc + 1) & 1];
        for (int s = grp; s < CHUNK; s += 3) {
          const float4* hq = (const float4*)&hstage[bufn][s][eoff];
          float a0 = 0.f, a1 = 0.f;
          #pragma unroll
          for (int k = 0; k < 13; ++k) {
            const float4 v = hq[k];
            a0 = fmaf(v.x, wr[4*k+0], a0);
            a1 = fmaf(v.y, wr[4*k+1], a1);
            a0 = fmaf(v.z, wr[4*k+2], a0);
            a1 = fmaf(v.w, wr[4*k+3], a1);
          }
          gw[s][col] = a0 + a1;
        }
      }
    } else {
      if (cc + 2 < NCHUNK) {
        const int bufs = (bufn == 2) ? 0 : bufn + 1;
        const float* hc = hb + (size_t)(cc + 2) * CHUNK * D;
        for (int s = 0; s < CHUNK; ++s) {
          const float* hr = hc + (size_t)s * D;
          hstage[bufs][s][lane] = hr[lane];
          if (lane < 40) hstage[bufs][s][64 + lane] = (lane < 36) ? hr[64 + lane] : 0.f;
        }
      }
    }
    __syncthreads();
    bufc = bufn;
  }
}

extern "C" void kernel_launch(void* const* d_in, const int* in_sizes, int n_in,
                              void* d_out, int out_size, void* d_ws, size_t ws_size,
                              hipStream_t stream) {
  const float* h   = (const float*)d_in[0];
  const float* dv  = (const float*)d_in[1];
  const float* w_c = (const float*)d_in[2];
  const float* w_s = (const float*)d_in[3];
  const float* w_r = (const float*)d_in[4];
  const float* pos = (const float*)d_in[5];
  const float* wap = (const float*)d_in[6];
  const float* bb  = (const float*)d_in[7];
  float* out = (float*)d_out;
  float* ab2m = (float*)d_ws;  // 2048 floats

  hipLaunchKernelGGL(k1_pos, dim3(TT / 256), dim3(256), 0, stream, pos, wap, bb, ab2m);
  hipLaunchKernelGGL(sp_scan, dim3(BB), dim3(NTHR), 0, stream,
                     h, dv, w_c, w_s, w_r, ab2m, out);
}